// Round 1
// 500.402 us; speedup vs baseline: 1.1219x; 1.1219x over previous
//
#include <hip/hip_runtime.h>

#define NDIM 512   // D_IN == D_OUT == 512

typedef __bf16 bf16x8 __attribute__((ext_vector_type(8)));
typedef float  f32x4  __attribute__((ext_vector_type(4)));

__device__ inline ushort f2bf(float f) {           // fp32 -> bf16 RNE
    uint b = __float_as_uint(f);
    return (ushort)((b + 0x7fffu + ((b >> 16) & 1u)) >> 16);
}
__device__ inline float bflo(uint u) { return __uint_as_float(u << 16); }
__device__ inline float bfhi(uint u) { return __uint_as_float(u & 0xffff0000u); }
__device__ inline uint packbf(float lo, float hi) {
    return ((uint)f2bf(hi) << 16) | (uint)f2bf(lo);
}

// async global->LDS, 16B per lane; lds base must be wave-uniform (dest = base + lane*16)
__device__ inline void gload16(const ushort* g, ushort* l) {
    __builtin_amdgcn_global_load_lds(
        (const __attribute__((address_space(1))) uint*)g,
        (__attribute__((address_space(3))) uint*)l, 16, 0, 0);
}

// ---------------- fp32 -> bf16 bulk convert (float4 -> ushort4) ----------------
__global__ __launch_bounds__(256) void f2bf_kernel(const float* __restrict__ in,
                                                   ushort* __restrict__ out, int n4) {
    int i = blockIdx.x * 256 + threadIdx.x;
    if (i >= n4) return;
    float4 v = ((const float4*)in)[i];
    ushort4 o;
    o.x = f2bf(v.x); o.y = f2bf(v.y); o.z = f2bf(v.z); o.w = f2bf(v.w);
    ((ushort4*)out)[i] = o;
}

// ---------------- histograms: deg_row[row]++, cnt_col[col]++ ----------------
__global__ __launch_bounds__(256) void hist_kernel(const int* __restrict__ ei,
                                                   int* __restrict__ deg_row,
                                                   int* __restrict__ cnt_col, int E) {
    int e = blockIdx.x * 256 + threadIdx.x;
    if (e < E) {
        atomicAdd(&deg_row[ei[e]], 1);
        atomicAdd(&cnt_col[ei[E + e]], 1);
    }
}

// ---------------- dis[i] = deg>0 ? rsqrt(deg) : 0 ----------------
__global__ __launch_bounds__(256) void rsqrt_kernel(const int* __restrict__ deg,
                                                    float* __restrict__ dis, int n) {
    int i = blockIdx.x * 256 + threadIdx.x;
    if (i < n) {
        int d = deg[i];
        dis[i] = (d > 0) ? rsqrtf((float)d) : 0.0f;
    }
}

// ------- single-block exclusive scan, 1024 thr x int4: base = exscan(cnt), base[n]=E -------
__global__ __launch_bounds__(1024) void scan_kernel(const int* __restrict__ cnt,
                                                    int* __restrict__ base, int n) {
    __shared__ int wsum[16];
    __shared__ int carry_s;
    int tid = threadIdx.x;
    int lane = tid & 63, wid = tid >> 6;
    if (tid == 0) carry_s = 0;
    __syncthreads();
    for (int s = 0; s < n; s += 4096) {
        int i0 = s + tid * 4;
        int v0 = 0, v1 = 0, v2 = 0, v3 = 0;
        if (i0 + 3 < n) {
            int4 q = *(const int4*)(cnt + i0);
            v0 = q.x; v1 = q.y; v2 = q.z; v3 = q.w;
        } else if (i0 < n) {
            v0 = cnt[i0];
            if (i0 + 1 < n) v1 = cnt[i0 + 1];
            if (i0 + 2 < n) v2 = cnt[i0 + 2];
        }
        int tsum = v0 + v1 + v2 + v3;
        int incl = tsum;
#pragma unroll
        for (int off = 1; off < 64; off <<= 1) {
            int t = __shfl_up(incl, off, 64);
            if (lane >= off) incl += t;
        }
        if (lane == 63) wsum[wid] = incl;
        __syncthreads();                      // wsum visible
        int add = carry_s;
#pragma unroll
        for (int w = 0; w < 16; ++w) if (w < wid) add += wsum[w];
        int run = add + incl - tsum;          // exclusive prefix of this thread's 4
        if (i0 + 0 < n) base[i0 + 0] = run; run += v0;
        if (i0 + 1 < n) base[i0 + 1] = run; run += v1;
        if (i0 + 2 < n) base[i0 + 2] = run; run += v2;
        if (i0 + 3 < n) base[i0 + 3] = run;
        __syncthreads();                      // all reads of carry_s/wsum done
        if (tid == 1023) carry_s = add + incl;
        __syncthreads();                      // carry_s visible
    }
    if (tid == 0) base[n] = carry_s;
}

// ---------------- fill CSR buckets with fused (row, norm) pairs per edge ----------------
__global__ __launch_bounds__(256) void fill_kernel(
        const int* __restrict__ ei, const float* __restrict__ ea,
        const float* __restrict__ dis,
        const float* __restrict__ conf_w, const float* __restrict__ conf_b,
        const int* __restrict__ base, int* __restrict__ fill_cnt,
        int2* __restrict__ rn_sorted, int E) {
    int e = blockIdx.x * 256 + threadIdx.x;
    if (e >= E) return;
    int row = ei[e];
    int col = ei[E + e];
    float w = ea[(size_t)e*3+0]*conf_w[0] + ea[(size_t)e*3+1]*conf_w[1]
            + ea[(size_t)e*3+2]*conf_w[2] + conf_b[0];
    w = 1.0f / (1.0f + __expf(-w));               // sigmoid
    float nm = dis[row] * dis[col] * w;
    int pos = base[col] + atomicAdd(&fill_cnt[col], 1);
    rn_sorted[pos] = make_int2(row, __float_as_int(nm));
}

// ------- gather-aggregate (bf16): aggh[node] = sum over bucket xh[row]*norm -------
// one WAVE per node (4 nodes / 256-thr block). Lane owns 8 channels (one 16B uint4
// gather per edge). Edge loop unrolled x4: 4 broadcast (row,norm) pair loads, then
// 4 independent 16B gathers in flight per wave -> breaks the index->gather latency
// chain that limited the half-block version. No LDS, no __syncthreads.
__global__ __launch_bounds__(256) void agg_kernel(
        const ushort* __restrict__ xh, const int2* __restrict__ rn,
        const int* __restrict__ base, ushort* __restrict__ aggh, int N) {
    int wid  = threadIdx.x >> 6;
    int lane = threadIdx.x & 63;
    int node = blockIdx.x * 4 + wid;
    if (node >= N) return;
    int start = base[node], end = base[node + 1];
    const ushort* xc = xh + lane * 8;             // this lane's 8-channel slice
    float a0 = 0.f, a1 = 0.f, a2 = 0.f, a3 = 0.f;
    float a4 = 0.f, a5 = 0.f, a6 = 0.f, a7 = 0.f;
    int p = start;
    for (; p + 4 <= end; p += 4) {
        int2 e0 = rn[p + 0];
        int2 e1 = rn[p + 1];
        int2 e2 = rn[p + 2];
        int2 e3 = rn[p + 3];
        uint4 u0 = *(const uint4*)(xc + ((size_t)e0.x << 9));
        uint4 u1 = *(const uint4*)(xc + ((size_t)e1.x << 9));
        uint4 u2 = *(const uint4*)(xc + ((size_t)e2.x << 9));
        uint4 u3 = *(const uint4*)(xc + ((size_t)e3.x << 9));
        float n0 = __int_as_float(e0.y);
        float n1 = __int_as_float(e1.y);
        float n2 = __int_as_float(e2.y);
        float n3 = __int_as_float(e3.y);
        a0 = fmaf(bflo(u0.x), n0, a0); a1 = fmaf(bfhi(u0.x), n0, a1);
        a2 = fmaf(bflo(u0.y), n0, a2); a3 = fmaf(bfhi(u0.y), n0, a3);
        a4 = fmaf(bflo(u0.z), n0, a4); a5 = fmaf(bfhi(u0.z), n0, a5);
        a6 = fmaf(bflo(u0.w), n0, a6); a7 = fmaf(bfhi(u0.w), n0, a7);
        a0 = fmaf(bflo(u1.x), n1, a0); a1 = fmaf(bfhi(u1.x), n1, a1);
        a2 = fmaf(bflo(u1.y), n1, a2); a3 = fmaf(bfhi(u1.y), n1, a3);
        a4 = fmaf(bflo(u1.z), n1, a4); a5 = fmaf(bfhi(u1.z), n1, a5);
        a6 = fmaf(bflo(u1.w), n1, a6); a7 = fmaf(bfhi(u1.w), n1, a7);
        a0 = fmaf(bflo(u2.x), n2, a0); a1 = fmaf(bfhi(u2.x), n2, a1);
        a2 = fmaf(bflo(u2.y), n2, a2); a3 = fmaf(bfhi(u2.y), n2, a3);
        a4 = fmaf(bflo(u2.z), n2, a4); a5 = fmaf(bfhi(u2.z), n2, a5);
        a6 = fmaf(bflo(u2.w), n2, a6); a7 = fmaf(bfhi(u2.w), n2, a7);
        a0 = fmaf(bflo(u3.x), n3, a0); a1 = fmaf(bfhi(u3.x), n3, a1);
        a2 = fmaf(bflo(u3.y), n3, a2); a3 = fmaf(bfhi(u3.y), n3, a3);
        a4 = fmaf(bflo(u3.z), n3, a4); a5 = fmaf(bfhi(u3.z), n3, a5);
        a6 = fmaf(bflo(u3.w), n3, a6); a7 = fmaf(bfhi(u3.w), n3, a7);
    }
    for (; p < end; ++p) {
        int2 e = rn[p];
        uint4 u = *(const uint4*)(xc + ((size_t)e.x << 9));
        float nm = __int_as_float(e.y);
        a0 = fmaf(bflo(u.x), nm, a0); a1 = fmaf(bfhi(u.x), nm, a1);
        a2 = fmaf(bflo(u.y), nm, a2); a3 = fmaf(bfhi(u.y), nm, a3);
        a4 = fmaf(bflo(u.z), nm, a4); a5 = fmaf(bfhi(u.z), nm, a5);
        a6 = fmaf(bflo(u.w), nm, a6); a7 = fmaf(bfhi(u.w), nm, a7);
    }
    uint4 o;
    o.x = packbf(a0, a1);
    o.y = packbf(a2, a3);
    o.z = packbf(a4, a5);
    o.w = packbf(a6, a7);
    *(uint4*)(aggh + (size_t)node * NDIM + lane * 8) = o;
}

// ---------------- bf16 MFMA GEMM (m97 structure): out = A @ B^T + bias ----------------
// 128x128 tile, BK=32, 256 threads = 4 waves, global_load_lds 16B staging,
// unpadded LDS [128][32] bf16 (64B rows) — the verified m97 layout
__global__ __launch_bounds__(256) void mfma_gemm(
        const ushort* __restrict__ A,   // [M][512] bf16 (agg)
        const ushort* __restrict__ B,   // [512][512] bf16, row = n (out), col = k (in)
        const float* __restrict__ bias,
        float* __restrict__ out, int M) {
    __shared__ ushort As[128 * 32];     // 8 KB
    __shared__ ushort Bs[128 * 32];     // 8 KB
    int m0 = blockIdx.x * 128;
    int n0 = blockIdx.y * 128;
    int tid  = threadIdx.x;
    int lane = tid & 63;
    int wave = tid >> 6;
    int wr = wave >> 1, wc = wave & 1;    // wave's 64x64 origin (wr*64, wc*64)
    int quad = lane >> 4, l16 = lane & 15;
    int lrow = lane >> 2, lcol = (lane & 3) << 3;   // staging: row-in-chunk, k-offset

    f32x4 acc[4][4] = {};                  // [mt][nt]

    for (int k0 = 0; k0 < NDIM; k0 += 32) {
        // stage A,B tiles: 8 chunks each of 16 rows x 32 k (1 KB); wave w does chunks 2w,2w+1
#pragma unroll
        for (int i = 0; i < 2; ++i) {
            int ch = wave * 2 + i;          // 0..7
            int r  = ch * 16 + lrow;        // 0..127
            int gm = m0 + r; if (gm >= M) gm = M - 1;   // clamp: junk rows never stored
            gload16(A + ((size_t)gm << 9) + k0 + lcol, &As[ch * 512]);
            gload16(B + ((size_t)(n0 + r) << 9) + k0 + lcol, &Bs[ch * 512]);
        }
        __syncthreads();
#pragma unroll
        for (int mt = 0; mt < 4; ++mt) {
            bf16x8 a = *(const bf16x8*)&As[(wr * 64 + mt * 16 + l16) * 32 + quad * 8];
#pragma unroll
            for (int nt = 0; nt < 4; ++nt) {
                bf16x8 b = *(const bf16x8*)&Bs[(wc * 64 + nt * 16 + l16) * 32 + quad * 8];
                acc[mt][nt] = __builtin_amdgcn_mfma_f32_16x16x32_bf16(a, b, acc[mt][nt], 0, 0, 0);
            }
        }
        __syncthreads();
    }
    // epilogue: C/D layout col = lane&15, row = quad*4 + reg
#pragma unroll
    for (int mt = 0; mt < 4; ++mt) {
#pragma unroll
        for (int nt = 0; nt < 4; ++nt) {
            int gn = n0 + wc * 64 + nt * 16 + l16;
            float bv = bias[gn];
#pragma unroll
            for (int r = 0; r < 4; ++r) {
                int gm = m0 + wr * 64 + mt * 16 + quad * 4 + r;
                if (gm < M) out[(size_t)gm * NDIM + gn] = acc[mt][nt][r] + bv;
            }
        }
    }
}

extern "C" void kernel_launch(void* const* d_in, const int* in_sizes, int n_in,
                              void* d_out, int out_size, void* d_ws, size_t ws_size,
                              hipStream_t stream) {
    const float* x      = (const float*)d_in[0];
    const int*   ei     = (const int*)  d_in[1];   // edge_index [2][E]
    const float* ea     = (const float*)d_in[2];   // edge_attr [E][3]
    const float* lin_w  = (const float*)d_in[3];   // [512][512]
    const float* lin_b  = (const float*)d_in[4];   // [512]
    const float* conf_w = (const float*)d_in[5];   // [3]
    const float* conf_b = (const float*)d_in[6];   // [1]
    float* out = (float*)d_out;

    int N = in_sizes[0] / NDIM;   // 50000
    int E = in_sizes[2] / 3;      // 800000

    // ---- workspace layout (256B aligned slabs) ----
    char* p = (char*)d_ws;
    auto alloc = [&](size_t bytes) {
        char* q = p;
        p += (bytes + 255) & ~(size_t)255;
        return q;
    };
    ushort* aggh       = (ushort*)alloc((size_t)N * NDIM * sizeof(ushort)); // 51.2 MB
    ushort* wh         = (ushort*)alloc((size_t)NDIM * NDIM * sizeof(ushort));
    int*   deg_row     = (int*)  alloc((size_t)N * sizeof(int));            // zeroed slab start
    int*   cnt_col     = (int*)  alloc((size_t)N * sizeof(int));            // zeroed
    int*   fill_cnt    = (int*)  alloc((size_t)N * sizeof(int));            // zeroed slab end
    float* dis         = (float*)alloc((size_t)N * sizeof(float));
    int*   base        = (int*)  alloc((size_t)(N + 1) * sizeof(int));
    int2*  rn_sorted   = (int2*) alloc((size_t)E * sizeof(int2));           // fused (row,norm)

    // xh (bf16 x, 51.2 MB) lives in the d_out buffer (102.4 MB): consumed by agg_kernel,
    // which completes (stream order) before mfma_gemm writes out.
    ushort* xh = (ushort*)d_out;

    size_t zero_bytes = (size_t)((char*)dis - (char*)deg_row);
    (void)hipMemsetAsync(deg_row, 0, zero_bytes, stream);

    int gE = (E + 255) / 256;
    int gN = (N + 255) / 256;
    int x4 = (N * NDIM) / 4, w4 = (NDIM * NDIM) / 4;
    f2bf_kernel  <<<(x4 + 255) / 256, 256, 0, stream>>>(x, xh, x4);
    f2bf_kernel  <<<(w4 + 255) / 256, 256, 0, stream>>>(lin_w, wh, w4);
    hist_kernel  <<<gE, 256, 0, stream>>>(ei, deg_row, cnt_col, E);
    rsqrt_kernel <<<gN, 256, 0, stream>>>(deg_row, dis, N);
    scan_kernel  <<<1, 1024, 0, stream>>>(cnt_col, base, N);
    fill_kernel  <<<gE, 256, 0, stream>>>(ei, ea, dis, conf_w, conf_b,
                                          base, fill_cnt, rn_sorted, E);
    agg_kernel   <<<(N + 3) / 4, 256, 0, stream>>>(xh, rn_sorted, base, aggh, N);
    dim3 g((N + 127) / 128, NDIM / 128);
    mfma_gemm    <<<g, 256, 0, stream>>>(aggh, wh, lin_b, out, N);
}